// Round 14
// baseline (447.438 us; speedup 1.0000x reference)
//
#include <hip/hip_runtime.h>
#include <hip/hip_bf16.h>
#include <hip/hip_cooperative_groups.h>

namespace cg = cooperative_groups;

// GCN layer, algebraically refactored:
//   hs[n]  = (x[n] @ W) * dis[n],   dis[n] = rsqrt(1 + sum_{e: col=n} w[e])
//   out[n] = relu( dis[n] * ( hs[n] + sum_{e: col=n} w[e] * hs[row[e]] ) + bias )
// Identical to PyG GCNConv (self-loops, symmetric norm) + ReLU.
// ALL phases fused into one cooperative kernel (grid.sync between phases) to
// eliminate 5 inter-kernel launch gaps. Phase logic identical to round 12
// (shared __device__ bodies); 6-kernel fallback if cooperative launch fails.

#define IN_C 128
#define HID_C 128
#define CAP 6144          // per-bucket edge capacity (mean 4082, +32 sigma)
#define EPB 4096          // standalone passA chunk
#define GRID_F 512        // fused grid: 48KB LDS -> 3 blocks/CU >= 2 needed

typedef __attribute__((ext_vector_type(8))) short bf16x8;
typedef __attribute__((ext_vector_type(4))) float f32x4;

// ---------- bf16 helpers (manual RNE) ----------
__device__ inline unsigned f2bf(float f) {
    unsigned u = __float_as_uint(f);
    return (u + 0x7FFFu + ((u >> 16) & 1u)) >> 16;
}
__device__ inline float bf_lo(unsigned v) { return __uint_as_float(v << 16); }
__device__ inline float bf_hi(unsigned v) { return __uint_as_float(v & 0xFFFF0000u); }

// ================= phase bodies (shared by fused + fallback) =================

// prep: W -> bf16 W^T pre-swizzled; block 0 zeroes gcur and sets ptr[N]=E.
__device__ inline void phz_prep(const float* __restrict__ W, unsigned short* __restrict__ wt,
                                int* __restrict__ gcur, int* __restrict__ ptr,
                                int E, int N, int bid) {
    const int t = threadIdx.x;
    if (bid == 0) { gcur[t] = 0; if (t == 0) ptr[N] = E; }
    int i = bid * 256 + t;
    if (i < 4096) {
        int n = i & 127;
        int k0 = (i >> 7) * 4;
        ushort4 bv;
        bv.x = (unsigned short)f2bf(W[(size_t)(k0 + 0) * HID_C + n]);
        bv.y = (unsigned short)f2bf(W[(size_t)(k0 + 1) * HID_C + n]);
        bv.z = (unsigned short)f2bf(W[(size_t)(k0 + 2) * HID_C + n]);
        bv.w = (unsigned short)f2bf(W[(size_t)(k0 + 3) * HID_C + n]);
        int idx = (n * 128 + k0) ^ ((n & 7) << 3);   // ushort-index swizzle
        *(ushort4*)&wt[idx] = bv;
    }
}

// passA: radix partition edges into 256-node buckets.
__device__ inline void phz_passA(const int* __restrict__ row, const int* __restrict__ col,
                                 const float* __restrict__ w, int* __restrict__ gcur,
                                 int2* __restrict__ bedge, int NBK, int e0, int e1,
                                 int* hist, int* base_s, int* cur) {
    const int t = threadIdx.x;
    hist[t] = 0;
    __syncthreads();
    for (int e = e0 + t; e < e1; e += 256) atomicAdd(&hist[col[e] >> 8], 1);
    __syncthreads();
    if (t < NBK && hist[t] > 0) base_s[t] = atomicAdd(&gcur[t], hist[t]);
    cur[t] = 0;
    __syncthreads();
    for (int e = e0 + t; e < e1; e += 256) {
        int c = col[e];
        int b = c >> 8;
        int lpos = atomicAdd(&cur[b], 1);
        int2 rec;
        rec.x = ((c & 255) << 24) | row[e];   // col_local | row (row < 2^24)
        rec.y = __float_as_int(w[e]);
        bedge[(size_t)b * CAP + base_s[b] + lpos] = rec;
    }
}

// passB: per-bucket — bucket scan, degree, dis, CSR ptr, node-sorted placement.
__device__ inline void phz_passB(const int2* __restrict__ bedge, const int* __restrict__ gcur,
                                 int2* __restrict__ sedge, int* __restrict__ ptr,
                                 float* __restrict__ dis, int N, int NBK, int b,
                                 float* wdeg, int* cnt, int* cur, int* sm, int* ebs, int* cnts) {
    const int t = threadIdx.x;
    const int nb0 = b << 8;
    int gv = (t < NBK) ? gcur[t] : 0;
    int gs = gv;
    sm[t] = gs;
    __syncthreads();
    for (int off = 1; off < 256; off <<= 1) {
        int add = (t >= off) ? sm[t - off] : 0;
        __syncthreads();
        gs += add;
        sm[t] = gs;
        __syncthreads();
    }
    ebs[t] = gs - gv;
    cnts[t] = gv;
    wdeg[t] = 0.f;
    cnt[t] = 0;
    __syncthreads();
    const int ecnt = cnts[b];
    const int eb   = ebs[b];
    const int2* be = bedge + (size_t)b * CAP;
    for (int p = t; p < ecnt; p += 256) {
        int2 rec = be[p];
        int cl = (rec.x >> 24) & 255;
        atomicAdd(&cnt[cl], 1);
        atomicAdd(&wdeg[cl], __int_as_float(rec.y));   // LDS f32 atomic
    }
    __syncthreads();
    int v = cnt[t];
    int s = v;
    sm[t] = s;
    __syncthreads();
    for (int off = 1; off < 256; off <<= 1) {
        int add = (t >= off) ? sm[t - off] : 0;
        __syncthreads();
        s += add;
        sm[t] = s;
        __syncthreads();
    }
    int excl = s - v;
    cur[t] = excl;
    int n = nb0 + t;
    if (n < N) {
        dis[n] = rsqrtf(1.0f + wdeg[t]);
        ptr[n] = eb + excl;
    }
    __syncthreads();
    for (int p = t; p < ecnt; p += 256) {
        int2 rec = be[p];
        int cl = (rec.x >> 24) & 255;
        int lpos = atomicAdd(&cur[cl], 1);
        int2 o;
        o.x = rec.x & 0xFFFFFF;
        o.y = rec.y;
        sedge[eb + lpos] = o;
    }
}

// gemm: stage pre-swizzled W^T (once per block), then per-64-row tile MFMA.
__device__ inline void phz_gemm_stageW(const unsigned short* __restrict__ wt,
                                       unsigned short* wsb) {
    for (int i = threadIdx.x; i < (128 * 128) / 8; i += 256)
        ((uint4*)wsb)[i] = ((const uint4*)wt)[i];
}

__device__ inline void phz_gemm_tile(const float* __restrict__ x, const float* __restrict__ dis,
                                     unsigned short* __restrict__ hsb,
                                     unsigned short* xsb, unsigned short* wsb,
                                     int base, int N) {
    const int t = threadIdx.x;
    for (int i = t; i < 64 * 32; i += 256) {
        int r = i >> 5;
        int c4 = (i & 31) * 4;
        int gr = base + r;
        if (gr >= N) gr = N - 1;
        float4 v = *(const float4*)&x[(size_t)gr * IN_C + c4];
        ushort4 bv;
        bv.x = (unsigned short)f2bf(v.x);
        bv.y = (unsigned short)f2bf(v.y);
        bv.z = (unsigned short)f2bf(v.z);
        bv.w = (unsigned short)f2bf(v.w);
        int idx = (r * 128 + c4) ^ ((r & 7) << 3);
        *(ushort4*)&xsb[idx] = bv;
    }
    __syncthreads();

    const int w  = t >> 6;
    const int l  = t & 63;
    const int lr = l & 15;
    const int lk = (l >> 4) * 8;

    f32x4 acc[8];
    #pragma unroll
    for (int nt = 0; nt < 8; ++nt) acc[nt] = (f32x4){0.f, 0.f, 0.f, 0.f};

    #pragma unroll
    for (int ks = 0; ks < 4; ++ks) {
        int k0 = ks * 32 + lk;
        int arow = w * 16 + lr;
        bf16x8 a = *(const bf16x8*)&xsb[(arow * 128 + k0) ^ ((arow & 7) << 3)];
        #pragma unroll
        for (int nt = 0; nt < 8; ++nt) {
            int bn = nt * 16 + lr;
            bf16x8 bb = *(const bf16x8*)&wsb[(bn * 128 + k0) ^ ((bn & 7) << 3)];
            acc[nt] = __builtin_amdgcn_mfma_f32_16x16x32_bf16(a, bb, acc[nt], 0, 0, 0);
        }
    }

    const int mbase = base + w * 16 + (l >> 4) * 4;
    float d[4];
    #pragma unroll
    for (int j = 0; j < 4; ++j)
        d[j] = (mbase + j < N) ? dis[mbase + j] : 0.f;
    #pragma unroll
    for (int nt = 0; nt < 8; ++nt) {
        int c = nt * 16 + lr;
        #pragma unroll
        for (int j = 0; j < 4; ++j) {
            int n = mbase + j;
            if (n < N)
                hsb[(size_t)n * HID_C + c] = (unsigned short)f2bf(acc[nt][j] * d[j]);
        }
    }
    __syncthreads();
}

// aggregate: one wave per node, 4 edge-slots x 16 lanes, record-prefetch pipeline.
__device__ inline void phz_agg(const uint4* __restrict__ hsb4, const int2* __restrict__ sedge,
                               const int* __restrict__ ptr, const float* __restrict__ dis,
                               const float* __restrict__ bias, float* __restrict__ out,
                               int n) {
    int lane = threadIdx.x & 63;
    int slot = lane >> 4;
    int cl   = lane & 15;

    int start = ptr[n];
    int end   = ptr[n + 1];

    uint4 sv = {0, 0, 0, 0};
    float4 b0 = {0, 0, 0, 0}, b1 = b0;
    if (slot == 0) {
        sv = hsb4[(size_t)n * 16 + cl];
        const float4* bp = (const float4*)(bias + cl * 8);
        b0 = bp[0];
        b1 = bp[1];
    }
    float d = dis[n];

    float acc[8];
    #pragma unroll
    for (int j = 0; j < 8; ++j) acc[j] = 0.f;

    int p = start + slot;
    int2 rec = (p < end) ? sedge[p] : make_int2(n, 0);   // wt=0 pad
    #pragma unroll 4
    for (int p0 = start; p0 < end; p0 += 4) {
        int pn = p0 + 4 + slot;
        int2 rec_next = (pn < end) ? sedge[pn] : make_int2(n, 0);
        float wt = __int_as_float(rec.y);
        uint4 v = hsb4[(size_t)rec.x * 16 + cl];
        acc[0] = fmaf(wt, bf_lo(v.x), acc[0]);
        acc[1] = fmaf(wt, bf_hi(v.x), acc[1]);
        acc[2] = fmaf(wt, bf_lo(v.y), acc[2]);
        acc[3] = fmaf(wt, bf_hi(v.y), acc[3]);
        acc[4] = fmaf(wt, bf_lo(v.z), acc[4]);
        acc[5] = fmaf(wt, bf_hi(v.z), acc[5]);
        acc[6] = fmaf(wt, bf_lo(v.w), acc[6]);
        acc[7] = fmaf(wt, bf_hi(v.w), acc[7]);
        rec = rec_next;
    }

    #pragma unroll
    for (int j = 0; j < 8; ++j) {
        acc[j] += __shfl_xor(acc[j], 16);
        acc[j] += __shfl_xor(acc[j], 32);
    }

    if (slot == 0) {
        acc[0] += bf_lo(sv.x); acc[1] += bf_hi(sv.x);
        acc[2] += bf_lo(sv.y); acc[3] += bf_hi(sv.y);
        acc[4] += bf_lo(sv.z); acc[5] += bf_hi(sv.z);
        acc[6] += bf_lo(sv.w); acc[7] += bf_hi(sv.w);
        float4 o0, o1;
        o0.x = fmaxf(fmaf(d, acc[0], b0.x), 0.f);
        o0.y = fmaxf(fmaf(d, acc[1], b0.y), 0.f);
        o0.z = fmaxf(fmaf(d, acc[2], b0.z), 0.f);
        o0.w = fmaxf(fmaf(d, acc[3], b0.w), 0.f);
        o1.x = fmaxf(fmaf(d, acc[4], b1.x), 0.f);
        o1.y = fmaxf(fmaf(d, acc[5], b1.y), 0.f);
        o1.z = fmaxf(fmaf(d, acc[6], b1.z), 0.f);
        o1.w = fmaxf(fmaf(d, acc[7], b1.w), 0.f);
        float4* op = (float4*)(out + (size_t)n * HID_C + cl * 8);
        op[0] = o0;
        op[1] = o1;
    }
}

// ================= fused cooperative kernel =================
__global__ __launch_bounds__(256, 2) void k_fused(const float* __restrict__ x,
                                                  const int* __restrict__ row,
                                                  const int* __restrict__ col,
                                                  const float* __restrict__ w,
                                                  const float* __restrict__ W,
                                                  const float* __restrict__ bias,
                                                  float* __restrict__ out,
                                                  int* gcur, int* ptr, float* dis,
                                                  unsigned short* wt, int2* bedge,
                                                  int2* sedge, unsigned short* hsb,
                                                  int E, int N, int NBK) {
    __shared__ __align__(16) unsigned char smem[49152];   // 48 KB, aliased per phase
    cg::grid_group grid = cg::this_grid();
    const int bid = blockIdx.x;
    const int gsz = gridDim.x;

    // phase 0: W prep + gcur zero
    phz_prep(W, wt, gcur, ptr, E, N, bid);
    grid.sync();

    // phase 1: bucket partition
    {
        int* ib = (int*)smem;
        int chunk = (E + gsz - 1) / gsz;
        int e0 = bid * chunk;
        int e1 = min(E, e0 + chunk);
        phz_passA(row, col, w, gcur, bedge, NBK, e0, e1, ib, ib + 256, ib + 512);
    }
    grid.sync();

    // phase 2: per-bucket CSR build
    if (bid < NBK) {
        float* fb = (float*)smem;
        int* ib = (int*)smem;
        phz_passB(bedge, gcur, sedge, ptr, dis, N, NBK, bid,
                  fb, ib + 256, ib + 512, ib + 768, ib + 1024, ib + 1280);
    }
    grid.sync();

    // phase 3: MFMA GEMM (grid-stride over 64-row tiles)
    {
        unsigned short* xsb = (unsigned short*)smem;
        unsigned short* wsb = (unsigned short*)(smem + 16384);
        phz_gemm_stageW(wt, wsb);
        int TL = (N + 63) >> 6;
        for (int tile = bid; tile < TL; tile += gsz)
            phz_gemm_tile(x, dis, hsb, xsb, wsb, tile * 64, N);
    }
    grid.sync();

    // phase 4: pull aggregation (grid-stride over 4-node groups)
    {
        int G = (N + 3) >> 2;
        for (int g = bid; g < G; g += gsz) {
            int n = g * 4 + (threadIdx.x >> 6);
            if (n < N) phz_agg((const uint4*)hsb, sedge, ptr, dis, bias, out, n);
        }
    }
}

// ================= fallback standalone kernels (round-12 path) =================
__global__ __launch_bounds__(256) void k_prepW_s(const float* W, unsigned short* wt,
                                                 int* gcur, int* ptr, int E, int N) {
    phz_prep(W, wt, gcur, ptr, E, N, blockIdx.x);
}

__global__ __launch_bounds__(256) void k_passA_s(const int* row, const int* col,
                                                 const float* w, int* gcur,
                                                 int2* bedge, int E, int NBK) {
    __shared__ int hist[256], base_s[256], cur[256];
    int e0 = blockIdx.x * EPB;
    int e1 = min(E, e0 + EPB);
    phz_passA(row, col, w, gcur, bedge, NBK, e0, e1, hist, base_s, cur);
}

__global__ __launch_bounds__(256) void k_passB_s(const int2* bedge, const int* gcur,
                                                 int2* sedge, int* ptr, float* dis,
                                                 int N, int NBK) {
    __shared__ float wdeg[256];
    __shared__ int cnt[256], cur[256], sm[256], ebs[256], cnts[256];
    phz_passB(bedge, gcur, sedge, ptr, dis, N, NBK, blockIdx.x,
              wdeg, cnt, cur, sm, ebs, cnts);
}

__global__ __launch_bounds__(256) void k_gemm_s(const float* x, const unsigned short* wt,
                                                const float* dis, unsigned short* hsb, int N) {
    __shared__ __align__(16) unsigned short xsb[64 * 128];
    __shared__ __align__(16) unsigned short wsb[128 * 128];
    phz_gemm_stageW(wt, wsb);
    phz_gemm_tile(x, dis, hsb, xsb, wsb, blockIdx.x * 64, N);
}

__global__ __launch_bounds__(256) void k_agg_s(const uint4* hsb4, const int2* sedge,
                                               const int* ptr, const float* dis,
                                               const float* bias, float* out, int N) {
    int n = blockIdx.x * 4 + (threadIdx.x >> 6);
    if (n < N) phz_agg(hsb4, sedge, ptr, dis, bias, out, n);
}

extern "C" void kernel_launch(void* const* d_in, const int* in_sizes, int n_in,
                              void* d_out, int out_size, void* d_ws, size_t ws_size,
                              hipStream_t stream) {
    const float* x    = (const float*)d_in[0];
    const int*   ei   = (const int*)d_in[1];
    const float* w    = (const float*)d_in[2];
    const float* W    = (const float*)d_in[3];
    const float* bias = (const float*)d_in[4];
    float* out = (float*)d_out;

    int E = in_sizes[2];
    int N = in_sizes[0] / IN_C;
    const int* row = ei;        // edge_index[0] (source)
    const int* col = ei + E;    // edge_index[1] (destination)
    int NBK = (N + 255) >> 8;   // 196 buckets of 256 nodes

    // workspace: gcur[256] | ptr[N+1] | dis[N] | wt[16384] ushort
    //            | bedge[NBK*CAP] int2 | sedge[E] int2 | hsb[N*128] ushort
    auto alup = [](size_t v) { return (v + 255) & ~(size_t)255; };
    char* p = (char*)d_ws;
    int*   gcur  = (int*)p;   p += alup(256 * 4);
    int*   ptr   = (int*)p;   p += alup(((size_t)N + 1) * 4);
    float* dis   = (float*)p; p += alup((size_t)N * 4);
    unsigned short* wt = (unsigned short*)p; p += alup(16384 * 2);
    int2*  bedge = (int2*)p;  p += alup((size_t)NBK * CAP * 8);
    int2*  sedge = (int2*)p;  p += alup((size_t)E * 8);
    unsigned short* hsb = (unsigned short*)p; p += alup((size_t)N * HID_C * 2);

    void* kargs[] = { &x, &row, &col, &w, &W, &bias, &out,
                      &gcur, &ptr, &dis, &wt, &bedge, &sedge, &hsb,
                      &E, &N, &NBK };
    hipError_t err = hipLaunchCooperativeKernel((const void*)k_fused, dim3(GRID_F),
                                                dim3(256), kargs, 0, stream);
    if (err != hipSuccess) {
        // deterministic fallback: the proven round-12 5-kernel path
        k_prepW_s<<<16, 256, 0, stream>>>(W, wt, gcur, ptr, E, N);
        k_passA_s<<<(E + EPB - 1) / EPB, 256, 0, stream>>>(row, col, w, gcur, bedge, E, NBK);
        k_passB_s<<<NBK, 256, 0, stream>>>(bedge, gcur, sedge, ptr, dis, N, NBK);
        k_gemm_s<<<(N + 63) / 64, 256, 0, stream>>>(x, wt, dis, hsb, N);
        k_agg_s<<<(N + 3) / 4, 256, 0, stream>>>((const uint4*)hsb, sedge, ptr,
                                                 dis, bias, out, N);
    }
}

// Round 15
// 180.141 us; speedup vs baseline: 2.4838x; 2.4838x over previous
//
#include <hip/hip_runtime.h>
#include <hip/hip_bf16.h>

// GCN layer, algebraically refactored:
//   hs[n]  = (x[n] @ W) * dis[n],   dis[n] = rsqrt(1 + sum_{e: col=n} w[e])
//   out[n] = relu( dis[n] * ( hs[n] + sum_{e: col=n} w[e] * hs[row[e]] ) + bias )
// Identical to PyG GCNConv (self-loops, symmetric norm) + ReLU.
// hs bf16; GEMM bf16 MFMA (fp32 accumulate); pull-based CSR aggregation.
// R14 lesson: cooperative fusion collapsed occupancy (23%) on the latency-bound
// aggregate -> reverted to 5-dispatch structure. This round: 2 nodes per wave in
// aggregate (dual independent gather chains), prepW merged into passA, EPB=8192.

#define IN_C 128
#define HID_C 128
#define CAP 6144          // per-bucket edge capacity (mean 4082, +32 sigma)
#define EPB 8192          // edges per pass-A block (32/thread; 98 blocks)

typedef __attribute__((ext_vector_type(8))) short bf16x8;
typedef __attribute__((ext_vector_type(4))) float f32x4;

// ---------- bf16 helpers (manual RNE) ----------
__device__ inline unsigned f2bf(float f) {
    unsigned u = __float_as_uint(f);
    return (u + 0x7FFFu + ((u >> 16) & 1u)) >> 16;
}
__device__ inline float bf_lo(unsigned v) { return __uint_as_float(v << 16); }
__device__ inline float bf_hi(unsigned v) { return __uint_as_float(v & 0xFFFF0000u); }

// ---------- pass A: radix partition + embedded W-prep (blocks 0-15) ----------
__global__ __launch_bounds__(256) void k_passA(const int* __restrict__ row,
                                               const int* __restrict__ col,
                                               const float* __restrict__ w,
                                               const float* __restrict__ W,
                                               unsigned short* __restrict__ wt,
                                               int* __restrict__ gcur,
                                               int2* __restrict__ bedge,
                                               int E, int NBK) {
    __shared__ int hist[256], base_s[256], cur[256];
    const int t = threadIdx.x;
    const int e0 = blockIdx.x * EPB;
    const int e1 = min(E, e0 + EPB);

    // embedded W-prep: wt[(n*128+k)^((n&7)<<3)] = bf16(W[k][n]) (pre-swizzled)
    int wi = blockIdx.x * 256 + t;
    if (wi < 4096) {
        int n = wi & 127;
        int k0 = (wi >> 7) * 4;
        ushort4 bv;
        bv.x = (unsigned short)f2bf(W[(size_t)(k0 + 0) * HID_C + n]);
        bv.y = (unsigned short)f2bf(W[(size_t)(k0 + 1) * HID_C + n]);
        bv.z = (unsigned short)f2bf(W[(size_t)(k0 + 2) * HID_C + n]);
        bv.w = (unsigned short)f2bf(W[(size_t)(k0 + 3) * HID_C + n]);
        int idx = (n * 128 + k0) ^ ((n & 7) << 3);
        *(ushort4*)&wt[idx] = bv;
    }

    hist[t] = 0;
    __syncthreads();

    int cbuf[EPB / 256];
    #pragma unroll
    for (int i = 0; i < EPB / 256; ++i) {
        int e = e0 + t + i * 256;
        int c = (e < e1) ? col[e] : -1;
        cbuf[i] = c;
        if (c >= 0) atomicAdd(&hist[c >> 8], 1);
    }
    __syncthreads();

    if (t < NBK && hist[t] > 0) base_s[t] = atomicAdd(&gcur[t], hist[t]);
    cur[t] = 0;
    __syncthreads();

    #pragma unroll
    for (int i = 0; i < EPB / 256; ++i) {
        int c = cbuf[i];
        if (c >= 0) {
            int e = e0 + t + i * 256;
            int b = c >> 8;
            int lpos = atomicAdd(&cur[b], 1);
            int2 rec;
            rec.x = ((c & 255) << 24) | row[e];   // col_local | row (row < 2^24)
            rec.y = __float_as_int(w[e]);
            bedge[(size_t)b * CAP + base_s[b] + lpos] = rec;
        }
    }
}

// ---------- pass B: per-bucket — bucket scan, degree, dis, CSR ptr, placement ----------
__global__ __launch_bounds__(256) void k_passB(const int2* __restrict__ bedge,
                                               const int* __restrict__ gcur,
                                               int2* __restrict__ sedge,
                                               int* __restrict__ ptr,
                                               float* __restrict__ dis,
                                               int E, int N, int NBK) {
    __shared__ float wdeg[256];
    __shared__ int cnt[256], cur[256], sm[256], ebs[256], cnts[256];
    const int b = blockIdx.x;
    const int t = threadIdx.x;
    const int nb0 = b << 8;

    // redundant per-block exclusive scan of bucket counts -> edge base
    int gv = (t < NBK) ? gcur[t] : 0;
    int gs = gv;
    sm[t] = gs;
    __syncthreads();
    for (int off = 1; off < 256; off <<= 1) {
        int add = (t >= off) ? sm[t - off] : 0;
        __syncthreads();
        gs += add;
        sm[t] = gs;
        __syncthreads();
    }
    ebs[t] = gs - gv;
    cnts[t] = gv;
    wdeg[t] = 0.f;
    cnt[t] = 0;
    __syncthreads();

    const int ecnt = cnts[b];
    const int eb   = ebs[b];
    const int2* be = bedge + (size_t)b * CAP;
    if (b == 0 && t == 0) ptr[N] = E;

    for (int p = t; p < ecnt; p += 256) {
        int2 rec = be[p];
        int cl = (rec.x >> 24) & 255;
        atomicAdd(&cnt[cl], 1);
        atomicAdd(&wdeg[cl], __int_as_float(rec.y));   // LDS f32 atomic
    }
    __syncthreads();

    // exclusive scan of per-node counts
    int v = cnt[t];
    int s = v;
    sm[t] = s;
    __syncthreads();
    for (int off = 1; off < 256; off <<= 1) {
        int add = (t >= off) ? sm[t - off] : 0;
        __syncthreads();
        s += add;
        sm[t] = s;
        __syncthreads();
    }
    int excl = s - v;
    cur[t] = excl;
    int n = nb0 + t;
    if (n < N) {
        dis[n] = rsqrtf(1.0f + wdeg[t]);
        ptr[n] = eb + excl;
    }
    __syncthreads();

    for (int p = t; p < ecnt; p += 256) {
        int2 rec = be[p];
        int cl = (rec.x >> 24) & 255;
        int lpos = atomicAdd(&cur[cl], 1);
        int2 o;
        o.x = rec.x & 0xFFFFFF;
        o.y = rec.y;
        sedge[eb + lpos] = o;
    }
}

// ---------- MFMA GEMM: hs(bf16) = (x @ W) * dis ----------
// 64 rows/block, full 128 cols. 4 waves; wave w owns rows [w*16, w*16+16).
// LDS: x tile bf16 [64][128] (converted here), W^T bf16 [128][128] copied
// linearly from pre-swizzled wt. Both XOR-swizzled (ushort idx ^= (row&7)<<3).
__global__ __launch_bounds__(256) void k_gemm_hs(const float* __restrict__ x,
                                                 const unsigned short* __restrict__ wt,
                                                 const float* __restrict__ dis,
                                                 unsigned short* __restrict__ hsb, int N) {
    __shared__ __align__(16) unsigned short xsb[64 * 128];    // 16 KB
    __shared__ __align__(16) unsigned short wsb[128 * 128];   // 32 KB

    const int t = threadIdx.x;
    const int base = blockIdx.x * 64;

    for (int i = t; i < (128 * 128) / 8; i += 256)
        ((uint4*)wsb)[i] = ((const uint4*)wt)[i];

    for (int i = t; i < 64 * 32; i += 256) {
        int r = i >> 5;
        int c4 = (i & 31) * 4;
        int gr = base + r;
        if (gr >= N) gr = N - 1;
        float4 v = *(const float4*)&x[(size_t)gr * IN_C + c4];
        ushort4 bv;
        bv.x = (unsigned short)f2bf(v.x);
        bv.y = (unsigned short)f2bf(v.y);
        bv.z = (unsigned short)f2bf(v.z);
        bv.w = (unsigned short)f2bf(v.w);
        int idx = (r * 128 + c4) ^ ((r & 7) << 3);
        *(ushort4*)&xsb[idx] = bv;
    }
    __syncthreads();

    const int w  = t >> 6;
    const int l  = t & 63;
    const int lr = l & 15;
    const int lk = (l >> 4) * 8;

    f32x4 acc[8];
    #pragma unroll
    for (int nt = 0; nt < 8; ++nt) acc[nt] = (f32x4){0.f, 0.f, 0.f, 0.f};

    #pragma unroll
    for (int ks = 0; ks < 4; ++ks) {
        int k0 = ks * 32 + lk;
        int arow = w * 16 + lr;
        bf16x8 a = *(const bf16x8*)&xsb[(arow * 128 + k0) ^ ((arow & 7) << 3)];
        #pragma unroll
        for (int nt = 0; nt < 8; ++nt) {
            int bn = nt * 16 + lr;
            bf16x8 bb = *(const bf16x8*)&wsb[(bn * 128 + k0) ^ ((bn & 7) << 3)];
            acc[nt] = __builtin_amdgcn_mfma_f32_16x16x32_bf16(a, bb, acc[nt], 0, 0, 0);
        }
    }

    // epilogue: D row = (l>>4)*4 + j, col = nt*16 + lr (m89-verified layout)
    const int mbase = base + w * 16 + (l >> 4) * 4;
    float d[4];
    #pragma unroll
    for (int j = 0; j < 4; ++j)
        d[j] = (mbase + j < N) ? dis[mbase + j] : 0.f;
    #pragma unroll
    for (int nt = 0; nt < 8; ++nt) {
        int c = nt * 16 + lr;
        #pragma unroll
        for (int j = 0; j < 4; ++j) {
            int n = mbase + j;
            if (n < N)
                hsb[(size_t)n * HID_C + c] = (unsigned short)f2bf(acc[nt][j] * d[j]);
        }
    }
}

// ---------- pull aggregation: one wave per TWO nodes, 4 slots x 16 lanes ----------
// Each wave interleaves two nodes' record->gather->fma chains (2x independent
// latency chains, half the trips, amortized combine/tail). Gather shape is the
// measured-optimal 4-slot x 16-lane x uint4. Record prefetch retained. After the
// butterfly, slot0 lanes finalize node0 and slot1 lanes finalize node1.
__global__ __launch_bounds__(256) void k_aggregate(const uint4* __restrict__ hsb4,
                                                   const int2* __restrict__ sedge,
                                                   const int* __restrict__ ptr,
                                                   const float* __restrict__ dis,
                                                   const float* __restrict__ bias,
                                                   float* __restrict__ out, int N) {
    int t = threadIdx.x;
    int nb = blockIdx.x * 8 + (t >> 6) * 2;   // wave covers nodes nb, nb+1
    if (nb >= N) return;
    int lane = t & 63;
    int slot = lane >> 4;      // 0..3
    int cl   = lane & 15;      // 16B chunk -> channels cl*8..cl*8+7

    const int n0 = nb;
    const bool has1 = (nb + 1 < N);
    const int n1 = has1 ? nb + 1 : nb;

    int s0 = ptr[n0], e0 = ptr[n0 + 1];
    int s1 = ptr[n1], e1 = ptr[n1 + 1];
    if (!has1) { s1 = 0; e1 = 0; }

    // early-issue finalization data (slot0 -> node0, slot1 -> node1)
    uint4 sv = {0, 0, 0, 0};
    float4 bv0 = {0, 0, 0, 0}, bv1 = bv0;
    if (slot == 0) {
        sv = hsb4[(size_t)n0 * 16 + cl];
        const float4* bp = (const float4*)(bias + cl * 8);
        bv0 = bp[0];
        bv1 = bp[1];
    } else if (slot == 1 && has1) {
        sv = hsb4[(size_t)n1 * 16 + cl];
        const float4* bp = (const float4*)(bias + cl * 8);
        bv0 = bp[0];
        bv1 = bp[1];
    }
    float d0 = dis[n0];
    float d1 = dis[n1];

    float a0[8], a1[8];
    #pragma unroll
    for (int j = 0; j < 8; ++j) { a0[j] = 0.f; a1[j] = 0.f; }

    int it0 = (e0 - s0 + 3) >> 2;
    int it1 = (e1 - s1 + 3) >> 2;
    int it = max(it0, it1);

    int p0 = s0 + slot, p1 = s1 + slot;
    int2 r0 = (p0 < e0) ? sedge[p0] : make_int2(n0, 0);   // wt=0 pad
    int2 r1 = (p1 < e1) ? sedge[p1] : make_int2(n1, 0);

    #pragma unroll 2
    for (int i = 0; i < it; ++i) {
        int q0 = s0 + (i + 1) * 4 + slot;
        int q1 = s1 + (i + 1) * 4 + slot;
        int2 r0n = (q0 < e0) ? sedge[q0] : make_int2(n0, 0);
        int2 r1n = (q1 < e1) ? sedge[q1] : make_int2(n1, 0);
        float w0 = __int_as_float(r0.y);
        float w1 = __int_as_float(r1.y);
        uint4 v0 = hsb4[(size_t)r0.x * 16 + cl];
        uint4 v1 = hsb4[(size_t)r1.x * 16 + cl];
        a0[0] = fmaf(w0, bf_lo(v0.x), a0[0]);
        a0[1] = fmaf(w0, bf_hi(v0.x), a0[1]);
        a0[2] = fmaf(w0, bf_lo(v0.y), a0[2]);
        a0[3] = fmaf(w0, bf_hi(v0.y), a0[3]);
        a0[4] = fmaf(w0, bf_lo(v0.z), a0[4]);
        a0[5] = fmaf(w0, bf_hi(v0.z), a0[5]);
        a0[6] = fmaf(w0, bf_lo(v0.w), a0[6]);
        a0[7] = fmaf(w0, bf_hi(v0.w), a0[7]);
        a1[0] = fmaf(w1, bf_lo(v1.x), a1[0]);
        a1[1] = fmaf(w1, bf_hi(v1.x), a1[1]);
        a1[2] = fmaf(w1, bf_lo(v1.y), a1[2]);
        a1[3] = fmaf(w1, bf_hi(v1.y), a1[3]);
        a1[4] = fmaf(w1, bf_lo(v1.z), a1[4]);
        a1[5] = fmaf(w1, bf_hi(v1.z), a1[5]);
        a1[6] = fmaf(w1, bf_lo(v1.w), a1[6]);
        a1[7] = fmaf(w1, bf_hi(v1.w), a1[7]);
        r0 = r0n;
        r1 = r1n;
    }

    // combine the 4 slots for both nodes (butterfly over ^16, ^32)
    #pragma unroll
    for (int j = 0; j < 8; ++j) {
        a0[j] += __shfl_xor(a0[j], 16);
        a0[j] += __shfl_xor(a0[j], 32);
        a1[j] += __shfl_xor(a1[j], 16);
        a1[j] += __shfl_xor(a1[j], 32);
    }

    if (slot == 0) {   // lanes 0..15: node0
        a0[0] += bf_lo(sv.x); a0[1] += bf_hi(sv.x);
        a0[2] += bf_lo(sv.y); a0[3] += bf_hi(sv.y);
        a0[4] += bf_lo(sv.z); a0[5] += bf_hi(sv.z);
        a0[6] += bf_lo(sv.w); a0[7] += bf_hi(sv.w);
        float4 o0, o1;
        o0.x = fmaxf(fmaf(d0, a0[0], bv0.x), 0.f);
        o0.y = fmaxf(fmaf(d0, a0[1], bv0.y), 0.f);
        o0.z = fmaxf(fmaf(d0, a0[2], bv0.z), 0.f);
        o0.w = fmaxf(fmaf(d0, a0[3], bv0.w), 0.f);
        o1.x = fmaxf(fmaf(d0, a0[4], bv1.x), 0.f);
        o1.y = fmaxf(fmaf(d0, a0[5], bv1.y), 0.f);
        o1.z = fmaxf(fmaf(d0, a0[6], bv1.z), 0.f);
        o1.w = fmaxf(fmaf(d0, a0[7], bv1.w), 0.f);
        float4* op = (float4*)(out + (size_t)n0 * HID_C + cl * 8);
        op[0] = o0;
        op[1] = o1;
    } else if (slot == 1 && has1) {   // lanes 16..31: node1
        a1[0] += bf_lo(sv.x); a1[1] += bf_hi(sv.x);
        a1[2] += bf_lo(sv.y); a1[3] += bf_hi(sv.y);
        a1[4] += bf_lo(sv.z); a1[5] += bf_hi(sv.z);
        a1[6] += bf_lo(sv.w); a1[7] += bf_hi(sv.w);
        float4 o0, o1;
        o0.x = fmaxf(fmaf(d1, a1[0], bv0.x), 0.f);
        o0.y = fmaxf(fmaf(d1, a1[1], bv0.y), 0.f);
        o0.z = fmaxf(fmaf(d1, a1[2], bv0.z), 0.f);
        o0.w = fmaxf(fmaf(d1, a1[3], bv0.w), 0.f);
        o1.x = fmaxf(fmaf(d1, a1[4], bv1.x), 0.f);
        o1.y = fmaxf(fmaf(d1, a1[5], bv1.y), 0.f);
        o1.z = fmaxf(fmaf(d1, a1[6], bv1.z), 0.f);
        o1.w = fmaxf(fmaf(d1, a1[7], bv1.w), 0.f);
        float4* op = (float4*)(out + (size_t)n1 * HID_C + cl * 8);
        op[0] = o0;
        op[1] = o1;
    }
}

extern "C" void kernel_launch(void* const* d_in, const int* in_sizes, int n_in,
                              void* d_out, int out_size, void* d_ws, size_t ws_size,
                              hipStream_t stream) {
    const float* x    = (const float*)d_in[0];
    const int*   ei   = (const int*)d_in[1];
    const float* w    = (const float*)d_in[2];
    const float* W    = (const float*)d_in[3];
    const float* bias = (const float*)d_in[4];
    float* out = (float*)d_out;

    const int N = in_sizes[0] / IN_C;
    const int E = in_sizes[2];
    const int* row = ei;        // edge_index[0] (source)
    const int* col = ei + E;    // edge_index[1] (destination)
    const int NBK = (N + 255) >> 8;   // 196 buckets of 256 nodes

    // workspace: gcur[256] | ptr[N+1] | dis[N] | wt[16384] ushort
    //            | bedge[NBK*CAP] int2 | sedge[E] int2 | hsb[N*128] ushort
    auto alup = [](size_t v) { return (v + 255) & ~(size_t)255; };
    char* p = (char*)d_ws;
    int*   gcur  = (int*)p;   p += alup(256 * 4);
    int*   ptr   = (int*)p;   p += alup(((size_t)N + 1) * 4);
    float* dis   = (float*)p; p += alup((size_t)N * 4);
    unsigned short* wt = (unsigned short*)p; p += alup(16384 * 2);
    int2*  bedge = (int2*)p;  p += alup((size_t)NBK * CAP * 8);
    int2*  sedge = (int2*)p;  p += alup((size_t)E * 8);
    unsigned short* hsb = (unsigned short*)p; p += alup((size_t)N * HID_C * 2);

    hipMemsetAsync(gcur, 0, 256 * 4, stream);

    k_passA<<<(E + EPB - 1) / EPB, 256, 0, stream>>>(row, col, w, W, wt, gcur,
                                                     bedge, E, NBK);
    k_passB<<<NBK, 256, 0, stream>>>(bedge, gcur, sedge, ptr, dis, E, N, NBK);

    k_gemm_hs<<<(N + 63) / 64, 256, 0, stream>>>(x, wt, dis, hsb, N);

    k_aggregate<<<(N + 7) / 8, 256, 0, stream>>>((const uint4*)hsb, sedge, ptr,
                                                 dis, bias, out, N);
}